// Round 6
// baseline (349.640 us; speedup 1.0000x reference)
//
#include <hip/hip_runtime.h>
#include <stdint.h>

#define NM 16
#define HW_P 589824            // 768*768 pixels per mask
#define U8PM 9216              // u64 words per mask
#define C4PM 4608              // uint4 chunks per mask
#define F4PM 147456            // float4s per mask
#define F4PT 2359296           // float4s per tensor
#define PT 512                 // threads per WG
#define NG 8                   // pipeline WGs (columns groups of 2)
#define NWG 128                // total WGs (>= 8*NG guarantees pigeonhole winner)
#define WGF4 36864             // float4s per WG slice (2*F4PT / NWG)
#define ITERS 72               // WGF4 / PT
#define MAGIC 0x51C0FFEEu

typedef unsigned long long u64;
typedef float vf4 __attribute__((ext_vector_type(4)));
typedef int v4i __attribute__((ext_vector_type(4)));

// meta (unsigned words): [0] init | [1] arrive | [2] pdone | [8..15] cnt[xcc]
// [16..31] flagsA | [32..47] flagsB | [48..55] cons | [64..175] prodflag[g*16+t]

__device__ __forceinline__ unsigned aload(unsigned* p) {
    return __hip_atomic_load(p, __ATOMIC_RELAXED, __HIP_MEMORY_SCOPE_AGENT);
}
__device__ __forceinline__ void astore(unsigned* p, unsigned v) {
    __hip_atomic_store(p, v, __ATOMIC_RELAXED, __HIP_MEMORY_SCOPE_AGENT);
}
__device__ __forceinline__ unsigned afadd(unsigned* p, unsigned v) {
    return __hip_atomic_fetch_add(p, v, __ATOMIC_RELAXED, __HIP_MEMORY_SCOPE_AGENT);
}

__device__ __forceinline__ uint32_t spread4(uint32_t x) {
    uint32_t t = (x | (x << 12)) & 0x000F000Fu;
    t = (t | (t << 6)) & 0x03030303u;
    t = (t | (t << 3)) & 0x11111111u;
    return t;
}

// 16-B load that bypasses L1 (sc0) and reads the XCD-shared L2 — the
// producer CU's plain stores land there (same XCD by construction).
__device__ __forceinline__ uint4 load16_sc0(const void* base, int voff) {
#if __has_builtin(__builtin_amdgcn_raw_buffer_load_v4f32)
    union { unsigned u[4]; v4i v; } r;
    r.u[0] = (unsigned)(uintptr_t)base;
    r.u[1] = (unsigned)((uintptr_t)base >> 32);
    r.u[2] = 0xFFFFFFFFu;          // num_records: bounds check off
    r.u[3] = 0x00020000u;          // raw dword SRD
    vf4 f = __builtin_amdgcn_raw_buffer_load_v4f32(r.v, voff, 0, 1 /*sc0*/);
    union { vf4 f; uint4 u; } c; c.f = f; return c.u;
#else
    const u64* p = (const u64*)((const char*)base + voff);
    u64 lo = __hip_atomic_load((u64*)p,       __ATOMIC_RELAXED, __HIP_MEMORY_SCOPE_AGENT);
    u64 hi = __hip_atomic_load((u64*)(p + 1), __ATOMIC_RELAXED, __HIP_MEMORY_SCOPE_AGENT);
    uint4 q;
    q.x = (uint32_t)lo; q.y = (uint32_t)(lo >> 32);
    q.z = (uint32_t)hi; q.w = (uint32_t)(hi >> 32);
    return q;
#endif
}

__global__ __launch_bounds__(PT, 1) void fused_kernel(
    const float* __restrict__ ma, const float* __restrict__ mb,
    const float* __restrict__ sa, const float* __restrict__ sb,
    uint32_t* bitsA, uint32_t* bitsB, int* meta, u64* msg, float* out)
{
    const int wg = blockIdx.x, tid = threadIdx.x;
    const int wave = tid >> 6, lane = tid & 63;
    unsigned* um = (unsigned*)meta;
    unsigned* init_f = um;
    unsigned* arrive = um + 1;
    unsigned* pdone  = um + 2;
    unsigned* cnt    = um + 8;
    int* flagsA      = meta + 16;
    int* flagsB      = meta + 32;
    unsigned* cons   = um + 48;
    unsigned* prodflag = um + 64;

    __shared__ int part[8][4];
    __shared__ unsigned smeta_s;
    __shared__ int s_slot, s_winner;

    // ================= phase 0: binarize slice =================
    const int tensor = (wg >= NWG / 2);
    {
        const float* src = tensor ? mb : ma;
        uint32_t* bits = tensor ? bitsB : bitsA;
        int lgbase = wg * WGF4 - (tensor ? F4PT : 0);
        for (int it = 0; it < ITERS; ++it) {
            int lg = lgbase + it * PT + tid;
            vf4 v = __builtin_nontemporal_load(((const vf4*)src) + lg);
            u64 q0 = __ballot(v.x > 0.0f);
            u64 q1 = __ballot(v.y > 0.0f);
            u64 q2 = __ballot(v.z > 0.0f);
            u64 q3 = __ballot(v.w > 0.0f);
            if (lane < 8) {
                uint32_t wd = spread4((uint32_t)(q0 >> (8 * lane)) & 0xFFu)
                            | (spread4((uint32_t)(q1 >> (8 * lane)) & 0xFFu) << 1)
                            | (spread4((uint32_t)(q2 >> (8 * lane)) & 0xFFu) << 2)
                            | (spread4((uint32_t)(q3 >> (8 * lane)) & 0xFFu) << 3);
                bits[((lg & ~63) >> 3) + lane] = wd;
            }
        }
    }
    // WG0 zeroes control words (ws is poisoned 0xAA every launch)
    if (wg == 0 && tid >= 1 && tid < 256) astore(um + tid, 0u);
    __threadfence();           // release binarize stores (+ zeroes) to L3
    __syncthreads();
    if (wg == 0 && tid == 0) astore(init_f, MAGIC);

    // ================= consensus: pick one XCD, 8 roles =================
    int xcc;
    asm volatile("s_getreg_b32 %0, hwreg(HW_REG_XCC_ID)" : "=s"(xcc));
    xcc &= 7;
    if (tid == 0) {
        while (aload(init_f) != MAGIC) __builtin_amdgcn_s_sleep(2);
        s_slot = (int)afadd(&cnt[xcc], 1u);
        afadd(arrive, 1u);
        while (aload(arrive) < NWG) __builtin_amdgcn_s_sleep(2);
        int wnr = 0;
        for (int x = 7; x >= 0; --x) if (aload(&cnt[x]) >= NG) wnr = x;
        s_winner = wnr;
    }
    __syncthreads();
    __threadfence();           // acquire: all binarize data + zeroed meta
    const bool participant = (xcc == s_winner) && (s_slot < NG);

    // ================= phase 1: systolic pipeline (8 WGs, one XCD) ========
    if (participant) {
        const int g = s_slot;
        const int c0 = 2 * g, c1 = 2 * g + 1;
        uint4* A4 = (uint4*)bitsA;
        uint4* B4 = (uint4*)bitsB;
        u64 a[18], b0[18], b1[18];

        int v0 = 0, v1 = 0;
#pragma unroll
        for (int w = 0; w < 9; ++w) {
            uint4 q0 = B4[(size_t)c0 * C4PM + tid + PT * w];
            uint4 q1 = B4[(size_t)c1 * C4PM + tid + PT * w];
            b0[2 * w] = ((u64)q0.y << 32) | q0.x; b0[2 * w + 1] = ((u64)q0.w << 32) | q0.z;
            b1[2 * w] = ((u64)q1.y << 32) | q1.x; b1[2 * w + 1] = ((u64)q1.w << 32) | q1.z;
            v0 += __popcll(b0[2 * w]) + __popcll(b0[2 * w + 1]);
            v1 += __popcll(b1[2 * w]) + __popcll(b1[2 * w + 1]);
        }
#pragma unroll
        for (int off = 32; off >= 1; off >>= 1) {
            v0 += __shfl_xor(v0, off); v1 += __shfl_xor(v1, off);
        }
        if (lane == 0) { part[wave][0] = v0; part[wave][1] = v1; }
        __syncthreads();
        int pcb0 = 0, pcb1 = 0;
#pragma unroll
        for (int w = 0; w < 8; ++w) { pcb0 += part[w][0]; pcb1 += part[w][1]; }
        __syncthreads();
        float sb0 = sb[c0], sb1 = sb[c1];
        int fb0 = 0, fb1 = 0;

        for (int t = 0; t < NM; ++t) {
            // ---- polls at stage start (R4 protocol — NOT R5's coupling) ----
            if (g > 0 && tid == 0) {
                unsigned v;
                while (!(v = aload(&prodflag[(g - 1) * 16 + t]))) {}
                smeta_s = v;
            }
            if (g < NG - 1 && t >= 4 && tid == 64) {
                while (aload(&cons[g]) < (unsigned)(t - 3)) {}
            }
            __syncthreads();   // B1

            int pca, fa;
            if (g == 0) {
                pca = 0; fa = 0;
#pragma unroll
                for (int w = 0; w < 9; ++w) {
                    uint4 q = A4[(size_t)t * C4PM + tid + PT * w];
                    a[2 * w] = ((u64)q.y << 32) | q.x;
                    a[2 * w + 1] = ((u64)q.w << 32) | q.z;
                }
            } else {
                unsigned mv = smeta_s;
                pca = (int)((mv >> 1) & 0xFFFFFu);
                fa  = (int)((mv >> 21) & 1u);
                const char* slot_in =
                    (const char*)(msg + (size_t)((g - 1) * 4 + (t & 3)) * U8PM);
#pragma unroll
                for (int w = 0; w < 9; ++w) {
                    uint4 q = load16_sc0(slot_in, tid * 16 + w * 8192);
                    a[2 * w] = ((u64)q.y << 32) | q.x;
                    a[2 * w + 1] = ((u64)q.w << 32) | q.z;
                }
            }

            int i0 = 0, i1 = 0, itr = 0, ipc = 0;
#pragma unroll
            for (int w = 0; w < 18; ++w) {
                u64 ab0 = a[w] & b0[w];
                i0 += __popcll(ab0);
                i1 += __popcll(a[w] & b1[w]);
                itr += __popcll(ab0 & b1[w]);
            }
            if (g == 0) {
#pragma unroll
                for (int w = 0; w < 18; ++w) ipc += __popcll(a[w]);
            }
#pragma unroll
            for (int off = 32; off >= 1; off >>= 1) {
                i0 += __shfl_xor(i0, off); i1 += __shfl_xor(i1, off);
                itr += __shfl_xor(itr, off); ipc += __shfl_xor(ipc, off);
            }
            if (lane == 0) {
                part[wave][0] = i0; part[wave][1] = i1;
                part[wave][2] = itr; part[wave][3] = ipc;
            }
            __syncthreads();   // B2: partials visible, slot loads retired
            if (g > 0 && tid == 65)
                astore(&cons[g - 1], (unsigned)(t + 1));
            int I0 = 0, I1 = 0, T = 0, PC = 0;
#pragma unroll
            for (int w = 0; w < 8; ++w) {
                I0 += part[w][0]; I1 += part[w][1];
                T  += part[w][2]; PC += part[w][3];
            }
            if (g == 0) pca = PC;

            float sai = sa[t];
            // ---- pair (t,c0): reference fp32 arithmetic exactly ----
            bool aupd = false;
            {
                int inter = I0;
                int uni = pca + pcb0 - inter;
                float iou = (float)inter / fmaxf((float)uni, 1.0f);
                bool aw = sai > sb0;
                if (iou > 0.8f) { if (aw) fb0 = 1; else fa = 1; }
                else if (inter > 0) {
                    if (aw) {
                        pcb0 -= inter;
#pragma unroll
                        for (int w = 0; w < 18; ++w) b0[w] &= ~a[w];
                    } else {
                        pca -= inter; aupd = true;
#pragma unroll
                        for (int w = 0; w < 18; ++w) a[w] &= ~b0[w];
                    }
                }
            }
            // ---- pair (t,c1): exact inter via speculative triple term ----
            {
                int inter = aupd ? (I1 - T) : I1;
                int uni = pca + pcb1 - inter;
                float iou = (float)inter / fmaxf((float)uni, 1.0f);
                bool aw = sai > sb1;
                if (iou > 0.8f) { if (aw) fb1 = 1; else fa = 1; }
                else if (inter > 0) {
                    if (aw) {
                        pcb1 -= inter;
#pragma unroll
                        for (int w = 0; w < 18; ++w) b1[w] &= ~a[w];
                    } else {
                        pca -= inter;
#pragma unroll
                        for (int w = 0; w < 18; ++w) a[w] &= ~b1[w];
                    }
                }
            }

            if (g < NG - 1) {
                uint4* so = (uint4*)(msg + (size_t)(g * 4 + (t & 3)) * U8PM);
#pragma unroll
                for (int w = 0; w < 9; ++w) {
                    uint4 q;
                    q.x = (uint32_t)a[2 * w];     q.y = (uint32_t)(a[2 * w] >> 32);
                    q.z = (uint32_t)a[2 * w + 1]; q.w = (uint32_t)(a[2 * w + 1] >> 32);
                    so[tid + PT * w] = q;          // plain: lands in shared L2
                }
                __threadfence_block();             // per-wave vmcnt drain
                __syncthreads();                   // B3: all waves drained
                if (tid == 0)
                    astore(&prodflag[g * 16 + t],
                           1u | ((unsigned)pca << 1) | ((unsigned)fa << 21));
            } else {
                uint4* Ar = A4 + (size_t)t * C4PM;
#pragma unroll
                for (int w = 0; w < 9; ++w) {
                    uint4 q;
                    q.x = (uint32_t)a[2 * w];     q.y = (uint32_t)(a[2 * w] >> 32);
                    q.z = (uint32_t)a[2 * w + 1]; q.w = (uint32_t)(a[2 * w + 1] >> 32);
                    Ar[tid + PT * w] = q;
                }
                if (tid == 0) flagsA[t] = fa;
                __syncthreads();                   // B3 (structure symmetry)
            }
        }

        // final b columns + flags
        uint4* Wc0 = B4 + (size_t)c0 * C4PM;
        uint4* Wc1 = B4 + (size_t)c1 * C4PM;
#pragma unroll
        for (int w = 0; w < 9; ++w) {
            uint4 q0, q1;
            q0.x = (uint32_t)b0[2 * w];     q0.y = (uint32_t)(b0[2 * w] >> 32);
            q0.z = (uint32_t)b0[2 * w + 1]; q0.w = (uint32_t)(b0[2 * w + 1] >> 32);
            q1.x = (uint32_t)b1[2 * w];     q1.y = (uint32_t)(b1[2 * w] >> 32);
            q1.z = (uint32_t)b1[2 * w + 1]; q1.w = (uint32_t)(b1[2 * w + 1] >> 32);
            Wc0[tid + PT * w] = q0;
            Wc1[tid + PT * w] = q1;
        }
        if (tid == 0) { flagsB[c0] = fb0; flagsB[c1] = fb1; }
        __threadfence();       // release all pipeline outputs to L3
        __syncthreads();
        if (tid == 0) afadd(pdone, 1u);
    }

    // ================= phase 2: expand slice =================
    if (tid == 0) { while (aload(pdone) < NG) __builtin_amdgcn_s_sleep(2); }
    __syncthreads();
    __threadfence();           // acquire pipeline outputs
    {
        const uint32_t* bits = tensor ? bitsB : bitsA;
        const int* flags = meta + (tensor ? 32 : 16);
        int lgbase = wg * WGF4 - (tensor ? F4PT : 0);
        for (int it = 0; it < ITERS; ++it) {
            int lg = lgbase + it * PT + tid;
            int m = lg / F4PM;
            bool keep = (flags[m] == 0);
            uint32_t wd = keep ? bits[lg >> 3] : 0u;
            int sh = (lg & 7) * 4;
            vf4 o;
            o.x = ((wd >> (sh + 0)) & 1u) ? 1.0f : 0.0f;
            o.y = ((wd >> (sh + 1)) & 1u) ? 1.0f : 0.0f;
            o.z = ((wd >> (sh + 2)) & 1u) ? 1.0f : 0.0f;
            o.w = ((wd >> (sh + 3)) & 1u) ? 1.0f : 0.0f;
            __builtin_nontemporal_store(o, ((vf4*)out) + (tensor ? lg + F4PT : lg));
        }
        if (wg == 0 && tid < 2 * NM)   // keep_a / keep_b tail
            out[(size_t)2 * NM * HW_P + tid] = meta[16 + tid] ? 0.0f : 1.0f;
    }
}

extern "C" void kernel_launch(void* const* d_in, const int* in_sizes, int n_in,
                              void* d_out, int out_size, void* d_ws, size_t ws_size,
                              hipStream_t stream)
{
    const float* ma = (const float*)d_in[0];
    const float* mb = (const float*)d_in[1];
    const float* sa = (const float*)d_in[2];
    const float* sb = (const float*)d_in[3];
    float* out = (float*)d_out;
    char* ws = (char*)d_ws;

    uint32_t* bitsA = (uint32_t*)(ws);             // 1,179,648 B
    uint32_t* bitsB = (uint32_t*)(ws + 1179648);   // 1,179,648 B
    int* meta       = (int*)(ws + 2359296);        // 1024 B (self-initialized)
    u64* msg        = (u64*)(ws + 2360320);        // 28 slots * 73,728 B

    fused_kernel<<<NWG, PT, 0, stream>>>(ma, mb, sa, sb,
                                         bitsA, bitsB, meta, msg, out);
}

// Round 8
// 227.460 us; speedup vs baseline: 1.5372x; 1.5372x over previous
//
#include <hip/hip_runtime.h>
#include <stdint.h>

#define NM 16
#define HW_P 589824            // 768*768 pixels per mask
#define U8PM 9216              // u64 words per mask
#define C4PM 4608              // uint4 chunks per mask
#define F4PM 147456            // float4s per mask
#define F4PT 2359296           // float4s per tensor
#define PT 512                 // pipeline threads per WG
#define NG 8                   // pipeline WGs (2 columns each)
#define EWG 64                 // election WGs (64 = 8*8: pigeonhole winner certain)

typedef unsigned long long u64;
typedef float vf4 __attribute__((ext_vector_type(4)));

// meta layout (unsigned words):
// [0..7] cnt[xcc] | [8] winner (0=unset else xcc+1) | [16..31] flagsA |
// [32..47] flagsB | [48+g*4] cons slot g (16B apart) |
// [80+(g*16+t)*4] prodflag (16B apart): bit0 valid | bits1..20 pca | bit21 fa

__device__ __forceinline__ unsigned aload(const unsigned* p) {
    return __hip_atomic_load(p, __ATOMIC_RELAXED, __HIP_MEMORY_SCOPE_AGENT);
}
__device__ __forceinline__ void astore(unsigned* p, unsigned v) {
    __hip_atomic_store(p, v, __ATOMIC_RELAXED, __HIP_MEMORY_SCOPE_AGENT);
}
__device__ __forceinline__ unsigned afadd(unsigned* p, unsigned v) {
    return __hip_atomic_fetch_add(p, v, __ATOMIC_RELAXED, __HIP_MEMORY_SCOPE_AGENT);
}
__device__ __forceinline__ u64 aload64(const u64* p) {
    return __hip_atomic_load(p, __ATOMIC_RELAXED, __HIP_MEMORY_SCOPE_AGENT);
}

__device__ __forceinline__ uint32_t spread4(uint32_t x) {
    uint32_t t = (x | (x << 12)) & 0x000F000Fu;
    t = (t | (t << 6)) & 0x03030303u;
    t = (t | (t << 3)) & 0x11111111u;
    return t;
}

// ---------------- kernel 1: binarize (coalesced) + meta zero ---------------
__global__ __launch_bounds__(256) void binarize_kernel(
    const float* __restrict__ ma, const float* __restrict__ mb,
    uint32_t* __restrict__ bitsA, uint32_t* __restrict__ bitsB,
    uint4* __restrict__ meta4)
{
    if (blockIdx.x == 0) {          // zero 4 KB of control state (ws is 0xAA)
        uint4 z; z.x = z.y = z.z = z.w = 0u;
        meta4[threadIdx.x] = z;
    }
    int g = blockIdx.x * 256 + threadIdx.x;        // float4 index
    int tensor = (g >= F4PT);                      // %64==0: wave-uniform
    int lg = tensor ? (g - F4PT) : g;
    const float* src = tensor ? mb : ma;
    vf4 v = __builtin_nontemporal_load(((const vf4*)src) + lg);
    u64 q0 = __ballot(v.x > 0.0f);
    u64 q1 = __ballot(v.y > 0.0f);
    u64 q2 = __ballot(v.z > 0.0f);
    u64 q3 = __ballot(v.w > 0.0f);
    int lane = threadIdx.x & 63;
    if (lane < 8) {
        uint32_t wd = spread4((uint32_t)(q0 >> (8 * lane)) & 0xFFu)
                    | (spread4((uint32_t)(q1 >> (8 * lane)) & 0xFFu) << 1)
                    | (spread4((uint32_t)(q2 >> (8 * lane)) & 0xFFu) << 2)
                    | (spread4((uint32_t)(q3 >> (8 * lane)) & 0xFFu) << 3);
        uint32_t* bits = tensor ? bitsB : bitsA;
        bits[((lg & ~63) >> 3) + lane] = wd;       // word = 8 float4s
    }
}

// ---------------- kernel 2: same-XCD systolic pipeline ---------------------
// 64 WGs; XCC election picks the first XCD to assemble 8 WGs, the other 56
// exit immediately. Messaging (R6-validated memory model): producer = plain
// write-through stores + __syncthreads vmcnt drain + agent flag store;
// consumer = agent flag poll + agent u64 loads. All traffic stays in the
// winner XCD's shared L2.
__global__ __launch_bounds__(PT, 1) void pipeline_kernel(
    const float* __restrict__ sa, const float* __restrict__ sb,
    uint32_t* bitsA, uint32_t* bitsB, unsigned* meta, u64* msg)
{
    unsigned* cnt    = meta;
    unsigned* winner = meta + 8;
    int* flagsA      = (int*)(meta + 16);
    int* flagsB      = (int*)(meta + 32);
    unsigned* consF  = meta + 48;
    unsigned* prodF  = meta + 80;

    const int tid = threadIdx.x;
    const int wave = tid >> 6, lane = tid & 63;

    __shared__ int s_g;
    __shared__ int part[8][4];
    __shared__ unsigned smeta_s;

    // ---- election (tid0), result broadcast via LDS ----
    if (tid == 0) {
        int xcc;
        asm volatile("s_getreg_b32 %0, hwreg(HW_REG_XCC_ID)" : "=s"(xcc));
        xcc &= 7;
        unsigned slot = afadd(&cnt[xcc], 1u);
        int mine = -1;
        if (slot < NG) {
            if (slot == NG - 1) {   // 8th reporter of this XCD claims the win
                unsigned exp = 0u;
                __hip_atomic_compare_exchange_strong(
                    winner, &exp, (unsigned)(xcc + 1),
                    __ATOMIC_RELAXED, __ATOMIC_RELAXED, __HIP_MEMORY_SCOPE_AGENT);
            }
            unsigned w;
            while (!(w = aload(winner))) __builtin_amdgcn_s_sleep(1);
            if (w == (unsigned)(xcc + 1)) mine = (int)slot;
        }
        s_g = mine;
    }
    __syncthreads();
    const int g = s_g;
    if (g < 0) return;              // 56 losers exit — zero interference

    const int c0 = 2 * g, c1 = 2 * g + 1;
    uint4* A4 = (uint4*)bitsA;
    uint4* B4 = (uint4*)bitsB;

    u64 a[18], b0[18], b1[18];

    // ---- load b columns (plain; dispatch boundary flushed binarize) ----
    int v0 = 0, v1 = 0;
#pragma unroll
    for (int w = 0; w < 9; ++w) {
        uint4 q0 = B4[(size_t)c0 * C4PM + tid + PT * w];
        uint4 q1 = B4[(size_t)c1 * C4PM + tid + PT * w];
        b0[2 * w] = ((u64)q0.y << 32) | q0.x; b0[2 * w + 1] = ((u64)q0.w << 32) | q0.z;
        b1[2 * w] = ((u64)q1.y << 32) | q1.x; b1[2 * w + 1] = ((u64)q1.w << 32) | q1.z;
        v0 += __popcll(b0[2 * w]) + __popcll(b0[2 * w + 1]);
        v1 += __popcll(b1[2 * w]) + __popcll(b1[2 * w + 1]);
    }
#pragma unroll
    for (int off = 32; off >= 1; off >>= 1) {
        v0 += __shfl_xor(v0, off); v1 += __shfl_xor(v1, off);
    }
    if (lane == 0) { part[wave][0] = v0; part[wave][1] = v1; }
    __syncthreads();
    int pcb0 = 0, pcb1 = 0;
#pragma unroll
    for (int w = 0; w < 8; ++w) { pcb0 += part[w][0]; pcb1 += part[w][1]; }
    float sb0 = sb[c0], sb1 = sb[c1];
    int fb0 = 0, fb1 = 0;

    for (int t = 0; t < NM; ++t) {
        // ---- polls at stage start (R4 protocol) ----
        if (g > 0 && tid == 0) {
            unsigned v;
            while (!(v = aload(&prodF[((g - 1) * 16 + t) * 4]))) {}
            smeta_s = v;
        }
        if (g < NG - 1 && t >= 4 && tid == 64) {
            while (aload(&consF[g * 4]) < (unsigned)(t - 3)) {}
        }
        __syncthreads();   // B1: flag seen, smeta visible, part[] free

        int pca, fa;
        if (g == 0) {
            pca = 0; fa = 0;
#pragma unroll
            for (int w = 0; w < 9; ++w) {
                uint4 q = A4[(size_t)t * C4PM + tid + PT * w];
                a[2 * w] = ((u64)q.y << 32) | q.x;
                a[2 * w + 1] = ((u64)q.w << 32) | q.z;
            }
        } else {
            unsigned mv = smeta_s;
            pca = (int)((mv >> 1) & 0xFFFFFu);
            fa  = (int)((mv >> 21) & 1u);
            const u64* slot_in = msg + (size_t)((g - 1) * 4 + (t & 3)) * U8PM;
#pragma unroll
            for (int w = 0; w < 9; ++w) {
                int base2 = 2 * tid + 1024 * w;
                a[2 * w]     = aload64(&slot_in[base2]);
                a[2 * w + 1] = aload64(&slot_in[base2 + 1]);
            }
        }

        // ---- fused popc terms (one reduction per row) ----
        int i0 = 0, i1 = 0, itr = 0, ipc = 0;
#pragma unroll
        for (int w = 0; w < 18; ++w) {
            u64 ab0 = a[w] & b0[w];
            i0 += __popcll(ab0);
            i1 += __popcll(a[w] & b1[w]);
            itr += __popcll(ab0 & b1[w]);
        }
        if (g == 0) {
#pragma unroll
            for (int w = 0; w < 18; ++w) ipc += __popcll(a[w]);
        }
#pragma unroll
        for (int off = 32; off >= 1; off >>= 1) {
            i0 += __shfl_xor(i0, off); i1 += __shfl_xor(i1, off);
            itr += __shfl_xor(itr, off); ipc += __shfl_xor(ipc, off);
        }
        if (lane == 0) {
            part[wave][0] = i0; part[wave][1] = i1;
            part[wave][2] = itr; part[wave][3] = ipc;
        }
        __syncthreads();   // B2: partials visible, slot loads retired
        if (g > 0 && tid == 65)            // slot consumed -> credit
            astore(&consF[(g - 1) * 4], (unsigned)(t + 1));
        int I0 = 0, I1 = 0, T = 0, PC = 0;
#pragma unroll
        for (int w = 0; w < 8; ++w) {
            I0 += part[w][0]; I1 += part[w][1];
            T  += part[w][2]; PC += part[w][3];
        }
        if (g == 0) pca = PC;

        float sai = sa[t];
        // ---- pair (t,c0): replicate reference fp32 arithmetic exactly ----
        bool aupd = false;
        {
            int inter = I0;
            int uni = pca + pcb0 - inter;
            float iou = (float)inter / fmaxf((float)uni, 1.0f);
            bool aw = sai > sb0;
            if (iou > 0.8f) { if (aw) fb0 = 1; else fa = 1; }
            else if (inter > 0) {
                if (aw) {
                    pcb0 -= inter;
#pragma unroll
                    for (int w = 0; w < 18; ++w) b0[w] &= ~a[w];
                } else {
                    pca -= inter; aupd = true;
#pragma unroll
                    for (int w = 0; w < 18; ++w) a[w] &= ~b0[w];
                }
            }
        }
        // ---- pair (t,c1): exact inter via speculative triple term ----
        {
            int inter = aupd ? (I1 - T) : I1;
            int uni = pca + pcb1 - inter;
            float iou = (float)inter / fmaxf((float)uni, 1.0f);
            bool aw = sai > sb1;
            if (iou > 0.8f) { if (aw) fb1 = 1; else fa = 1; }
            else if (inter > 0) {
                if (aw) {
                    pcb1 -= inter;
#pragma unroll
                    for (int w = 0; w < 18; ++w) b1[w] &= ~a[w];
                } else {
                    pca -= inter;
#pragma unroll
                    for (int w = 0; w < 18; ++w) a[w] &= ~b1[w];
                }
            }
        }

        // ---- forward / finalize row ----
        if (g < NG - 1) {
            uint4* so = (uint4*)(msg + (size_t)(g * 4 + (t & 3)) * U8PM);
#pragma unroll
            for (int w = 0; w < 9; ++w) {
                uint4 q;
                q.x = (uint32_t)a[2 * w];     q.y = (uint32_t)(a[2 * w] >> 32);
                q.z = (uint32_t)a[2 * w + 1]; q.w = (uint32_t)(a[2 * w + 1] >> 32);
                so[tid + PT * w] = q;          // plain: write-through into L2
            }
            __syncthreads();   // B3: every wave's vmcnt(0) -> data in L2
            if (tid == 0)      // flag strictly after data
                astore(&prodF[(g * 16 + t) * 4],
                       1u | ((unsigned)pca << 1) | ((unsigned)fa << 21));
        } else {
            uint4* Ar = A4 + (size_t)t * C4PM;
#pragma unroll
            for (int w = 0; w < 9; ++w) {
                uint4 q;
                q.x = (uint32_t)a[2 * w];     q.y = (uint32_t)(a[2 * w] >> 32);
                q.z = (uint32_t)a[2 * w + 1]; q.w = (uint32_t)(a[2 * w + 1] >> 32);
                Ar[tid + PT * w] = q;
            }
            if (tid == 0) flagsA[t] = fa;
            __syncthreads();   // keep loop structure symmetric
        }
    }

    // final b columns + flags; dispatch-end flush publishes to expand
    uint4* Wc0 = B4 + (size_t)c0 * C4PM;
    uint4* Wc1 = B4 + (size_t)c1 * C4PM;
#pragma unroll
    for (int w = 0; w < 9; ++w) {
        uint4 q0, q1;
        q0.x = (uint32_t)b0[2 * w];     q0.y = (uint32_t)(b0[2 * w] >> 32);
        q0.z = (uint32_t)b0[2 * w + 1]; q0.w = (uint32_t)(b0[2 * w + 1] >> 32);
        q1.x = (uint32_t)b1[2 * w];     q1.y = (uint32_t)(b1[2 * w] >> 32);
        q1.z = (uint32_t)b1[2 * w + 1]; q1.w = (uint32_t)(b1[2 * w + 1] >> 32);
        Wc0[tid + PT * w] = q0;
        Wc1[tid + PT * w] = q1;
    }
    if (tid == 0) { flagsB[c0] = fb0; flagsB[c1] = fb1; }
}

// ---------------- kernel 3: expand (coalesced, NT stores) ------------------
__global__ __launch_bounds__(256) void expand_kernel(
    const uint32_t* __restrict__ bitsA, const uint32_t* __restrict__ bitsB,
    const int* __restrict__ meta, float* __restrict__ out)
{
    int g = blockIdx.x * 256 + threadIdx.x;        // float4 index
    int tensor = (g >= F4PT);
    int lg = tensor ? (g - F4PT) : g;
    const uint32_t* bits = tensor ? bitsB : bitsA;
    const int* flags = meta + (tensor ? 32 : 16);
    int m = lg / F4PM;
    bool keep = (flags[m] == 0);
    uint32_t wd = keep ? bits[lg >> 3] : 0u;
    int sh = (lg & 7) * 4;
    vf4 o;
    o.x = ((wd >> (sh + 0)) & 1u) ? 1.0f : 0.0f;
    o.y = ((wd >> (sh + 1)) & 1u) ? 1.0f : 0.0f;
    o.z = ((wd >> (sh + 2)) & 1u) ? 1.0f : 0.0f;
    o.w = ((wd >> (sh + 3)) & 1u) ? 1.0f : 0.0f;
    __builtin_nontemporal_store(o, ((vf4*)out) + g);
    if (g < 2 * NM) {   // keep_a / keep_b tail (flagsA,flagsB contiguous)
        out[(size_t)2 * NM * HW_P + g] = meta[16 + g] ? 0.0f : 1.0f;
    }
}

extern "C" void kernel_launch(void* const* d_in, const int* in_sizes, int n_in,
                              void* d_out, int out_size, void* d_ws, size_t ws_size,
                              hipStream_t stream)
{
    const float* ma = (const float*)d_in[0];
    const float* mb = (const float*)d_in[1];
    const float* sa = (const float*)d_in[2];
    const float* sb = (const float*)d_in[3];
    float* out = (float*)d_out;
    char* ws = (char*)d_ws;

    uint32_t* bitsA = (uint32_t*)(ws);             // 1,179,648 B
    uint32_t* bitsB = (uint32_t*)(ws + 1179648);   // 1,179,648 B
    unsigned* meta  = (unsigned*)(ws + 2359296);   // 4096 B, zeroed by binarize
    u64* msg        = (u64*)(ws + 2363392);        // 28 slots * 73,728 B

    binarize_kernel<<<18432, 256, 0, stream>>>(ma, mb, bitsA, bitsB,
                                               (uint4*)meta);
    pipeline_kernel<<<EWG, PT, 0, stream>>>(sa, sb, bitsA, bitsB, meta, msg);
    expand_kernel<<<18432, 256, 0, stream>>>(bitsA, bitsB, (const int*)meta, out);
}

// Round 9
// 226.772 us; speedup vs baseline: 1.5418x; 1.0030x over previous
//
#include <hip/hip_runtime.h>
#include <stdint.h>

#define NM 16
#define HW_P 589824            // 768*768 pixels per mask
#define U8PM 9216              // u64 words per mask
#define C4PM 4608              // uint4 chunks per mask
#define F4PM 147456            // float4s per mask
#define F4PT 2359296           // float4s per tensor
#define PT 512                 // pipeline threads per WG
#define NG 8                   // pipeline WGs (2 columns each)
#define EWG 64                 // election WGs (64 = 8*8: pigeonhole winner certain)

typedef unsigned long long u64;
typedef float vf4 __attribute__((ext_vector_type(4)));

// meta layout (unsigned words):
// [0..7] cnt[xcc] | [8] winner (0=unset else xcc+1) | [16..31] flagsA |
// [32..47] flagsB | [48+g*4] cons slot g (16B apart) |
// [80+(g*16+t)*4] prodflag (16B apart): bit0 valid | bits1..20 pca | bit21 fa

__device__ __forceinline__ unsigned aload(const unsigned* p) {
    return __hip_atomic_load(p, __ATOMIC_RELAXED, __HIP_MEMORY_SCOPE_AGENT);
}
__device__ __forceinline__ void astore(unsigned* p, unsigned v) {
    __hip_atomic_store(p, v, __ATOMIC_RELAXED, __HIP_MEMORY_SCOPE_AGENT);
}
__device__ __forceinline__ unsigned afadd(unsigned* p, unsigned v) {
    return __hip_atomic_fetch_add(p, v, __ATOMIC_RELAXED, __HIP_MEMORY_SCOPE_AGENT);
}
__device__ __forceinline__ u64 aload64(const u64* p) {
    return __hip_atomic_load(p, __ATOMIC_RELAXED, __HIP_MEMORY_SCOPE_AGENT);
}

__device__ __forceinline__ uint32_t spread4(uint32_t x) {
    uint32_t t = (x | (x << 12)) & 0x000F000Fu;
    t = (t | (t << 6)) & 0x03030303u;
    t = (t | (t << 3)) & 0x11111111u;
    return t;
}

// ---------------- kernel 1: binarize (coalesced) + meta zero ---------------
__global__ __launch_bounds__(256) void binarize_kernel(
    const float* __restrict__ ma, const float* __restrict__ mb,
    uint32_t* __restrict__ bitsA, uint32_t* __restrict__ bitsB,
    uint4* __restrict__ meta4)
{
    if (blockIdx.x == 0) {          // zero 4 KB of control state (ws is 0xAA)
        uint4 z; z.x = z.y = z.z = z.w = 0u;
        meta4[threadIdx.x] = z;
    }
    int g = blockIdx.x * 256 + threadIdx.x;        // float4 index
    int tensor = (g >= F4PT);                      // %64==0: wave-uniform
    int lg = tensor ? (g - F4PT) : g;
    const float* src = tensor ? mb : ma;
    vf4 v = __builtin_nontemporal_load(((const vf4*)src) + lg);
    u64 q0 = __ballot(v.x > 0.0f);
    u64 q1 = __ballot(v.y > 0.0f);
    u64 q2 = __ballot(v.z > 0.0f);
    u64 q3 = __ballot(v.w > 0.0f);
    int lane = threadIdx.x & 63;
    if (lane < 8) {
        uint32_t wd = spread4((uint32_t)(q0 >> (8 * lane)) & 0xFFu)
                    | (spread4((uint32_t)(q1 >> (8 * lane)) & 0xFFu) << 1)
                    | (spread4((uint32_t)(q2 >> (8 * lane)) & 0xFFu) << 2)
                    | (spread4((uint32_t)(q3 >> (8 * lane)) & 0xFFu) << 3);
        uint32_t* bits = tensor ? bitsB : bitsA;
        bits[((lg & ~63) >> 3) + lane] = wd;       // word = 8 float4s
    }
}

// ---------------- kernel 2: same-XCD systolic pipeline, 2 barriers/stage ---
// 64 WGs; XCC election picks the first XCD to assemble 8 WGs, the other 56
// exit immediately. R8-validated messaging (plain stores + vmcnt drain +
// agent flag; agent loads), but the stage protocol is trimmed: ALL waves poll
// the in-flag directly (no B1 barrier, no LDS broadcast — flag word carries
// pca/fa), and the producer credit check is wave-autonomous before stores.
__global__ __launch_bounds__(PT, 1) void pipeline_kernel(
    const float* __restrict__ sa, const float* __restrict__ sb,
    uint32_t* bitsA, uint32_t* bitsB, unsigned* meta, u64* msg)
{
    unsigned* cnt    = meta;
    unsigned* winner = meta + 8;
    int* flagsA      = (int*)(meta + 16);
    int* flagsB      = (int*)(meta + 32);
    unsigned* consF  = meta + 48;
    unsigned* prodF  = meta + 80;

    const int tid = threadIdx.x;
    const int wave = tid >> 6, lane = tid & 63;

    __shared__ int s_g;
    __shared__ int4 part[8];

    // ---- election (tid0), result broadcast via LDS ----
    if (tid == 0) {
        int xcc;
        asm volatile("s_getreg_b32 %0, hwreg(HW_REG_XCC_ID)" : "=s"(xcc));
        xcc &= 7;
        unsigned slot = afadd(&cnt[xcc], 1u);
        int mine = -1;
        if (slot < NG) {
            if (slot == NG - 1) {   // 8th reporter of this XCD claims the win
                unsigned exp = 0u;
                __hip_atomic_compare_exchange_strong(
                    winner, &exp, (unsigned)(xcc + 1),
                    __ATOMIC_RELAXED, __ATOMIC_RELAXED, __HIP_MEMORY_SCOPE_AGENT);
            }
            unsigned w;
            while (!(w = aload(winner))) __builtin_amdgcn_s_sleep(1);
            if (w == (unsigned)(xcc + 1)) mine = (int)slot;
        }
        s_g = mine;
    }
    __syncthreads();
    const int g = s_g;
    if (g < 0) return;              // 56 losers exit — zero interference

    const int c0 = 2 * g, c1 = 2 * g + 1;
    uint4* A4 = (uint4*)bitsA;
    uint4* B4 = (uint4*)bitsB;

    u64 b0[18], b1[18];

    // ---- load b columns (plain; dispatch boundary flushed binarize) ----
    int v0 = 0, v1 = 0;
#pragma unroll
    for (int w = 0; w < 9; ++w) {
        uint4 q0 = B4[(size_t)c0 * C4PM + tid + PT * w];
        uint4 q1 = B4[(size_t)c1 * C4PM + tid + PT * w];
        b0[2 * w] = ((u64)q0.y << 32) | q0.x; b0[2 * w + 1] = ((u64)q0.w << 32) | q0.z;
        b1[2 * w] = ((u64)q1.y << 32) | q1.x; b1[2 * w + 1] = ((u64)q1.w << 32) | q1.z;
        v0 += __popcll(b0[2 * w]) + __popcll(b0[2 * w + 1]);
        v1 += __popcll(b1[2 * w]) + __popcll(b1[2 * w + 1]);
    }
#pragma unroll
    for (int off = 32; off >= 1; off >>= 1) {
        v0 += __shfl_xor(v0, off); v1 += __shfl_xor(v1, off);
    }
    if (lane == 0) { int4 p; p.x = v0; p.y = v1; p.z = 0; p.w = 0; part[wave] = p; }
    __syncthreads();
    int pcb0 = 0, pcb1 = 0;
#pragma unroll
    for (int w = 0; w < 8; ++w) { pcb0 += part[w].x; pcb1 += part[w].y; }
    float sb0 = sb[c0], sb1 = sb[c1];
    int fb0 = 0, fb1 = 0;
    __syncthreads();   // part[] free for stage 0 writes

    for (int t = 0; t < NM; ++t) {
        int pca, fa;
        u64 a[18];

        // ---- obtain row t: every wave polls the flag, then loads at once ---
        if (g == 0) {
            pca = 0; fa = 0;
#pragma unroll
            for (int w = 0; w < 9; ++w) {
                uint4 q = A4[(size_t)t * C4PM + tid + PT * w];
                a[2 * w] = ((u64)q.y << 32) | q.x;
                a[2 * w + 1] = ((u64)q.w << 32) | q.z;
            }
        } else {
            const unsigned* fptr = &prodF[((g - 1) * 16 + t) * 4];
            unsigned v;
            do { v = aload(fptr); } while (!v);
            asm volatile("" ::: "memory");   // pin data loads below the poll
            pca = (int)((v >> 1) & 0xFFFFFu);
            fa  = (int)((v >> 21) & 1u);
            const u64* slot_in = msg + (size_t)((g - 1) * 4 + (t & 3)) * U8PM;
#pragma unroll
            for (int w = 0; w < 9; ++w) {
                int base2 = 2 * tid + 1024 * w;
                a[2 * w]     = aload64(&slot_in[base2]);
                a[2 * w + 1] = aload64(&slot_in[base2 + 1]);
            }
        }

        // ---- fused popc terms (one reduction per row) ----
        int i0 = 0, i1 = 0, itr = 0, ipc = 0;
#pragma unroll
        for (int w = 0; w < 18; ++w) {
            u64 ab0 = a[w] & b0[w];
            i0 += __popcll(ab0);
            i1 += __popcll(a[w] & b1[w]);
            itr += __popcll(ab0 & b1[w]);
        }
        if (g == 0) {
#pragma unroll
            for (int w = 0; w < 18; ++w) ipc += __popcll(a[w]);
        }
#pragma unroll
        for (int off = 32; off >= 1; off >>= 1) {
            i0 += __shfl_xor(i0, off); i1 += __shfl_xor(i1, off);
            itr += __shfl_xor(itr, off); ipc += __shfl_xor(ipc, off);
        }
        if (lane == 0) {
            int4 p; p.x = i0; p.y = i1; p.z = itr; p.w = ipc; part[wave] = p;
        }
        __syncthreads();   // B2: partials visible, slot loads retired
        if (g > 0 && tid == 65)            // slot consumed -> credit
            astore(&consF[(g - 1) * 4], (unsigned)(t + 1));
        int I0 = 0, I1 = 0, T = 0, PC = 0;
#pragma unroll
        for (int w = 0; w < 8; ++w) {
            int4 p = part[w];
            I0 += p.x; I1 += p.y; T += p.z; PC += p.w;
        }
        if (g == 0) pca = PC;

        float sai = sa[t];
        // ---- pair (t,c0): replicate reference fp32 arithmetic exactly ----
        bool aupd = false;
        {
            int inter = I0;
            int uni = pca + pcb0 - inter;
            float iou = (float)inter / fmaxf((float)uni, 1.0f);
            bool aw = sai > sb0;
            if (iou > 0.8f) { if (aw) fb0 = 1; else fa = 1; }
            else if (inter > 0) {
                if (aw) {
                    pcb0 -= inter;
#pragma unroll
                    for (int w = 0; w < 18; ++w) b0[w] &= ~a[w];
                } else {
                    pca -= inter; aupd = true;
#pragma unroll
                    for (int w = 0; w < 18; ++w) a[w] &= ~b0[w];
                }
            }
        }
        // ---- pair (t,c1): exact inter via speculative triple term ----
        {
            int inter = aupd ? (I1 - T) : I1;
            int uni = pca + pcb1 - inter;
            float iou = (float)inter / fmaxf((float)uni, 1.0f);
            bool aw = sai > sb1;
            if (iou > 0.8f) { if (aw) fb1 = 1; else fa = 1; }
            else if (inter > 0) {
                if (aw) {
                    pcb1 -= inter;
#pragma unroll
                    for (int w = 0; w < 18; ++w) b1[w] &= ~a[w];
                } else {
                    pca -= inter;
#pragma unroll
                    for (int w = 0; w < 18; ++w) a[w] &= ~b1[w];
                }
            }
        }

        // ---- forward / finalize row ----
        if (g < NG - 1) {
            if (t >= 4) {   // wave-autonomous credit check (rarely blocks)
                const unsigned* cp = &consF[g * 4];
                while (aload(cp) < (unsigned)(t - 3)) {}
                asm volatile("" ::: "memory");
            }
            uint4* so = (uint4*)(msg + (size_t)(g * 4 + (t & 3)) * U8PM);
#pragma unroll
            for (int w = 0; w < 9; ++w) {
                uint4 q;
                q.x = (uint32_t)a[2 * w];     q.y = (uint32_t)(a[2 * w] >> 32);
                q.z = (uint32_t)a[2 * w + 1]; q.w = (uint32_t)(a[2 * w + 1] >> 32);
                so[tid + PT * w] = q;          // plain: write-through into L2
            }
            __syncthreads();   // B3: every wave's vmcnt(0) -> data in L2
            if (tid == 0)      // flag strictly after data
                astore(&prodF[(g * 16 + t) * 4],
                       1u | ((unsigned)pca << 1) | ((unsigned)fa << 21));
        } else {
            uint4* Ar = A4 + (size_t)t * C4PM;
#pragma unroll
            for (int w = 0; w < 9; ++w) {
                uint4 q;
                q.x = (uint32_t)a[2 * w];     q.y = (uint32_t)(a[2 * w] >> 32);
                q.z = (uint32_t)a[2 * w + 1]; q.w = (uint32_t)(a[2 * w + 1] >> 32);
                Ar[tid + PT * w] = q;
            }
            if (tid == 0) flagsA[t] = fa;
            __syncthreads();   // B3: part[] anti-race across stages
        }
    }

    // final b columns + flags; dispatch-end flush publishes to expand
    uint4* Wc0 = B4 + (size_t)c0 * C4PM;
    uint4* Wc1 = B4 + (size_t)c1 * C4PM;
#pragma unroll
    for (int w = 0; w < 9; ++w) {
        uint4 q0, q1;
        q0.x = (uint32_t)b0[2 * w];     q0.y = (uint32_t)(b0[2 * w] >> 32);
        q0.z = (uint32_t)b0[2 * w + 1]; q0.w = (uint32_t)(b0[2 * w + 1] >> 32);
        q1.x = (uint32_t)b1[2 * w];     q1.y = (uint32_t)(b1[2 * w] >> 32);
        q1.z = (uint32_t)b1[2 * w + 1]; q1.w = (uint32_t)(b1[2 * w + 1] >> 32);
        Wc0[tid + PT * w] = q0;
        Wc1[tid + PT * w] = q1;
    }
    if (tid == 0) { flagsB[c0] = fb0; flagsB[c1] = fb1; }
}

// ---------------- kernel 3: expand (coalesced, NT stores) ------------------
__global__ __launch_bounds__(256) void expand_kernel(
    const uint32_t* __restrict__ bitsA, const uint32_t* __restrict__ bitsB,
    const int* __restrict__ meta, float* __restrict__ out)
{
    int g = blockIdx.x * 256 + threadIdx.x;        // float4 index
    int tensor = (g >= F4PT);
    int lg = tensor ? (g - F4PT) : g;
    const uint32_t* bits = tensor ? bitsB : bitsA;
    const int* flags = meta + (tensor ? 32 : 16);
    int m = lg / F4PM;
    bool keep = (flags[m] == 0);
    uint32_t wd = keep ? bits[lg >> 3] : 0u;
    int sh = (lg & 7) * 4;
    vf4 o;
    o.x = ((wd >> (sh + 0)) & 1u) ? 1.0f : 0.0f;
    o.y = ((wd >> (sh + 1)) & 1u) ? 1.0f : 0.0f;
    o.z = ((wd >> (sh + 2)) & 1u) ? 1.0f : 0.0f;
    o.w = ((wd >> (sh + 3)) & 1u) ? 1.0f : 0.0f;
    __builtin_nontemporal_store(o, ((vf4*)out) + g);
    if (g < 2 * NM) {   // keep_a / keep_b tail (flagsA,flagsB contiguous)
        out[(size_t)2 * NM * HW_P + g] = meta[16 + g] ? 0.0f : 1.0f;
    }
}

extern "C" void kernel_launch(void* const* d_in, const int* in_sizes, int n_in,
                              void* d_out, int out_size, void* d_ws, size_t ws_size,
                              hipStream_t stream)
{
    const float* ma = (const float*)d_in[0];
    const float* mb = (const float*)d_in[1];
    const float* sa = (const float*)d_in[2];
    const float* sb = (const float*)d_in[3];
    float* out = (float*)d_out;
    char* ws = (char*)d_ws;

    uint32_t* bitsA = (uint32_t*)(ws);             // 1,179,648 B
    uint32_t* bitsB = (uint32_t*)(ws + 1179648);   // 1,179,648 B
    unsigned* meta  = (unsigned*)(ws + 2359296);   // 4096 B, zeroed by binarize
    u64* msg        = (u64*)(ws + 2363392);        // 28 slots * 73,728 B

    binarize_kernel<<<18432, 256, 0, stream>>>(ma, mb, bitsA, bitsB,
                                               (uint4*)meta);
    pipeline_kernel<<<EWG, PT, 0, stream>>>(sa, sb, bitsA, bitsB, meta, msg);
    expand_kernel<<<18432, 256, 0, stream>>>(bitsA, bitsB, (const int*)meta, out);
}